// Round 2
// 388.050 us; speedup vs baseline: 1.0207x; 1.0207x over previous
//
#include <hip/hip_runtime.h>
#include <hip/hip_fp16.h>

// Problem constants (fixed by the reference): B=4, D=8, H=512, W=640, 16 neighbors.
constexpr int BB = 4, DD = 8, HH = 512, WW = 640, NB = 16;
constexpr int NTOT = DD + NB;   // 24 values sorted per pixel
constexpr int HWST = HH * WW;   // channel stride
constexpr size_t Q_BYTES = (size_t)BB * HWST * 8;   // fp16 quad texture: 10.5 MB

// Prevent the compiler from sinking already-issued loads past this point.
#define ISSUE_BARRIER() asm volatile("" ::: "memory")

// Compile-time Batcher / Knuth merge-exchange sorting network for NTOT=24 (127 CEs).
struct Net { int a[160]; int b[160]; int n; };
constexpr Net make_net() {
    Net net{}; net.n = 0;
    const int N = NTOT;
    int t = 0; while ((1 << t) < N) ++t;
    for (int p = 1 << (t - 1); p > 0; p >>= 1) {
        int q = 1 << (t - 1), r = 0, d = p;
        for (;;) {
            for (int i = 0; i < N - d; ++i)
                if ((i & p) == r) { net.a[net.n] = i; net.b[net.n] = i + d; ++net.n; }
            if (q == p) break;
            d = q - p; q >>= 1; r = p;
        }
    }
    return net;
}

// ---------------------------------------------------------------------------
// Pre-pass: build fp16 quad texture Q[b][y][x] = {v00, v01, v10, v11} with
// border clamping baked in. 8B/entry, 2.6 MB per batch. Same XCD swizzle as
// the main kernel (b = bid & 3) so each quad image lands in the consuming L2s.
// Stores are REGULAR (L2-allocating) on purpose: they pre-warm Q in L2.
__global__ __launch_bounds__(128) void quad_prepass(
    const float* __restrict__ depth, uint2* __restrict__ Q)
{
    const int bid = blockIdx.x;                 // 0 .. 4*5*512-1
    const int b   = bid & 3;
    const int r   = bid >> 2;                   // 0 .. 2559
    const int wb  = r % 5;
    const int y   = r / 5;
    const int x   = wb * 128 + threadIdx.x;

    const float* __restrict__ img = depth + ((size_t)b * DD + DD / 2) * HWST;
    const int x1 = min(x + 1, WW - 1);
    const int y1 = min(y + 1, HH - 1);
    float v00 = img[y  * WW + x];
    float v01 = img[y  * WW + x1];
    float v10 = img[y1 * WW + x];
    float v11 = img[y1 * WW + x1];
    __half2 t = __floats2half2_rn(v00, v01);
    __half2 bo = __floats2half2_rn(v10, v11);
    uint2 q;
    q.x = *(const unsigned int*)&t;
    q.y = *(const unsigned int*)&bo;
    Q[(size_t)b * HWST + y * WW + x] = q;
}

// ---------------------------------------------------------------------------
// Main kernel: one thread per pixel, gather-latency-bound. This version:
//   * grid loads issued FIRST (critical path to the gather addresses).
//   * 16 gathers via __hip_atomic_load(RELAXED, AGENT) — agent-scope loads
//     emit global_load_dwordx2 sc0: L1 BYPASS, still cached in L2. The L1
//     hit rate on a 2.6 MB random footprint is ~0%, but each 8B gather was
//     paying a 64B L2->L1 line fill + L1 MSHR/tag occupancy (~8x
//     amplification on the saturated path). sc0 removes that while keeping
//     Q resident in the per-XCD L2 the prepass warmed. NOT nontemporal:
//     nt would deprioritize Q in L2.
//     Using the atomic builtin (not inline asm) keeps the loads inside the
//     compiler's vmcnt bookkeeping, so it emits its own correct
//     fine-grained counted waits as the quads are consumed in issue order.
//   * depth loads issued AFTER the gathers: consumed only by the sort, so
//     they ride behind the gathers in the vmcnt queue and their latency
//     hides under interpolation.
__global__ __launch_bounds__(128) void Propagation_kernel(
    const float* __restrict__ depth,   // [B, D, H, W]
    const float* __restrict__ grid,    // [B, NB*H, W, 2]
    const uint2* __restrict__ Q,       // [B, H, W] fp16 quads
    float* __restrict__ out)           // [B, D+NB, H, W] sorted along dim 1
{
    const int bid = blockIdx.x;
    const int b   = bid & 3;           // XCD = bid % 8 -> batch b on XCDs {b, b+4}
    const int r   = bid >> 2;
    const int wb  = r % 5;
    const int h   = r / 5;
    const int w   = wb * 128 + threadIdx.x;
    const int hw  = h * WW + w;

    const uint2* __restrict__ Qb = Q + (size_t)b * HWST;
    const float* __restrict__ gbase = grid + (((size_t)b * NB * HH + h) * WW + w) * 2;

    // ---- Phase 0: issue ALL 16 grid loads (critical path to gather addrs).
    unsigned long long gbits[NB];
#pragma unroll
    for (int n = 0; n < NB; ++n)
        gbits[n] = __builtin_nontemporal_load(
            (const unsigned long long*)(gbase + (size_t)n * HH * WW * 2));
    ISSUE_BARRIER();

    // ---- Phase 1: coords -> offsets + weights.
    float wxa[NB], wya[NB];
    int off[NB];
#pragma unroll
    for (int n = 0; n < NB; ++n) {
        float gx = __uint_as_float((unsigned int)gbits[n]);
        float gy = __uint_as_float((unsigned int)(gbits[n] >> 32));
        float x = ((gx + 1.0f) * (float)WW - 1.0f) * 0.5f;
        float y = ((gy + 1.0f) * (float)HH - 1.0f) * 0.5f;
        x = fminf(fmaxf(x, 0.0f), (float)(WW - 1));
        y = fminf(fmaxf(y, 0.0f), (float)(HH - 1));
        float x0f = floorf(x), y0f = floorf(y);
        wxa[n] = x - x0f;
        wya[n] = y - y0f;
        off[n] = (int)y0f * WW + (int)x0f;
    }

    // ---- Phase 1b: issue all 16 L1-bypass gathers (sc0 via agent-scope
    // relaxed atomic load; compiler-tracked vmcnt).
    unsigned long long qb[NB];
#pragma unroll
    for (int n = 0; n < NB; ++n) {
        const unsigned long long* p =
            (const unsigned long long*)(Qb + off[n]);
        qb[n] = __hip_atomic_load(p, __ATOMIC_RELAXED, __HIP_MEMORY_SCOPE_AGENT);
    }
    ISSUE_BARRIER();

    // ---- Phase 2: depth streaming loads (consumed only at sort time) —
    // issued after the gathers so their latency hides under interpolation.
    float v[NTOT];
#pragma unroll
    for (int d = 0; d < DD; ++d)
        v[d] = __builtin_nontemporal_load(depth + ((size_t)b * DD + d) * HWST + hw);
    ISSUE_BARRIER();

    // ---- Phase 3: bilinear interpolation in fp32 (consumes quads in issue
    // order; compiler emits decreasing vmcnt waits).
#pragma unroll
    for (int n = 0; n < NB; ++n) {
        unsigned int lo = (unsigned int)qb[n];
        unsigned int hi = (unsigned int)(qb[n] >> 32);
        float2 t  = __half22float2(__builtin_bit_cast(__half2, lo));  // v00, v01
        float2 bo = __half22float2(__builtin_bit_cast(__half2, hi));  // v10, v11
        float ti = fmaf(wxa[n], t.y - t.x, t.x);
        float bi = fmaf(wxa[n], bo.y - bo.x, bo.x);
        v[DD + n] = fmaf(wya[n], bi - ti, ti);
    }

    // ---- Sort 24 values ascending (unrolled network; constant indices only).
    constexpr Net net = make_net();
#pragma unroll
    for (int k = 0; k < net.n; ++k) {
        const int ia = net.a[k], ib = net.b[k];
        float lo = fminf(v[ia], v[ib]);
        float hi = fmaxf(v[ia], v[ib]);
        v[ia] = lo; v[ib] = hi;
    }

    // ---- 24 coalesced nontemporal channel stores (keep output OUT of L2:
    // Q must stay resident there).
    float* __restrict__ obase = out + (size_t)b * NTOT * HWST + hw;
#pragma unroll
    for (int c = 0; c < NTOT; ++c)
        __builtin_nontemporal_store(v[c], obase + (size_t)c * HWST);
}

// ---------------------------------------------------------------------------
// Fallback (no workspace needed) in case ws_size < Q_BYTES.
__global__ __launch_bounds__(128) void Propagation_fallback(
    const float* __restrict__ depth, const float* __restrict__ grid,
    float* __restrict__ out)
{
    const int w = blockIdx.x * 128 + threadIdx.x;
    const int h = blockIdx.y;
    const int b = blockIdx.z;
    const int hw = h * WW + w;
    const float* __restrict__ img = depth + ((size_t)b * DD + DD / 2) * HWST;
    float v[NTOT];
#pragma unroll
    for (int d = 0; d < DD; ++d)
        v[d] = depth[((size_t)b * DD + d) * HWST + hw];
    const float* __restrict__ gbase = grid + (((size_t)b * NB * HH + h) * WW + w) * 2;
#pragma unroll
    for (int n = 0; n < NB; ++n) {
        float2 g = *(const float2*)(gbase + (size_t)n * HH * WW * 2);
        float x = ((g.x + 1.0f) * (float)WW - 1.0f) * 0.5f;
        float y = ((g.y + 1.0f) * (float)HH - 1.0f) * 0.5f;
        x = fminf(fmaxf(x, 0.0f), (float)(WW - 1));
        y = fminf(fmaxf(y, 0.0f), (float)(HH - 1));
        float x0f = floorf(x), y0f = floorf(y);
        float wx = x - x0f, wy = y - y0f;
        int x0 = (int)x0f, y0 = (int)y0f;
        float2 t, bo;
        __builtin_memcpy(&t,  img + y0 * WW + x0,      sizeof(float2));
        __builtin_memcpy(&bo, img + y0 * WW + x0 + WW, sizeof(float2));
        float ti = fmaf(wx, t.y - t.x, t.x);
        float bi = fmaf(wx, bo.y - bo.x, bo.x);
        v[DD + n] = fmaf(wy, bi - ti, ti);
    }
    constexpr Net net = make_net();
#pragma unroll
    for (int k = 0; k < net.n; ++k) {
        const int ia = net.a[k], ib = net.b[k];
        float lo = fminf(v[ia], v[ib]);
        float hi = fmaxf(v[ia], v[ib]);
        v[ia] = lo; v[ib] = hi;
    }
    float* __restrict__ obase = out + (size_t)b * NTOT * HWST + hw;
#pragma unroll
    for (int c = 0; c < NTOT; ++c)
        __builtin_nontemporal_store(v[c], obase + (size_t)c * HWST);
}

extern "C" void kernel_launch(void* const* d_in, const int* in_sizes, int n_in,
                              void* d_out, int out_size, void* d_ws, size_t ws_size,
                              hipStream_t stream) {
    const float* depth = (const float*)d_in[3];
    const float* grid  = (const float*)d_in[4];
    float* out = (float*)d_out;

    if (ws_size >= Q_BYTES) {
        uint2* Q = (uint2*)d_ws;
        const int nblk = BB * (WW / 128) * HH;   // 10240
        quad_prepass<<<nblk, 128, 0, stream>>>(depth, Q);
        Propagation_kernel<<<nblk, 128, 0, stream>>>(depth, grid, Q, out);
    } else {
        dim3 grd(WW / 128, HH, BB);
        Propagation_fallback<<<grd, dim3(128), 0, stream>>>(depth, grid, out);
    }
}